// Round 8
// baseline (61.359 us; speedup 1.0000x reference)
//
#include <hip/hip_runtime.h>
#include <hip/hip_bf16.h>

// Edge MLP via MFMA, round 8: force the outstanding-miss product.
// r7 evidence: VGPR_Count=64 -> compiler sank the m1 gathers past m0 compute
// (can't hold 16 u32x4 in 64 regs), so only ~8 loads in flight; 64+16acc regs
// -> 4 waves/SIMD cap, measured 2.8. Product ~22 outstanding/SIMD.
// Fix: __launch_bounds__(256,4) (VGPR cap 128) + issue ALL 16 gathers then
// __builtin_amdgcn_sched_barrier(0) -- a scheduling-region boundary the
// compiler cannot sink loads across -> 64 live dest VGPRs, 16 in flight/wave,
// 4 waves/SIMD: 64 outstanding/SIMD (pool math: 4*(64+~45)=436 <= 512).

#define NEDGE 600000
#define NNODES 50000
#define DIN 128
#define DH 64
#define STRK 136       // LDS row stride (shorts)
#define HCVT 6250      // h-convert blocks
#define WCVT 8         // W1^T blocks
#define MAINB 4688     // ceil(600000/128)

typedef __attribute__((ext_vector_type(8))) short bf16x8;
typedef __attribute__((ext_vector_type(4))) float f32x4;
typedef __attribute__((ext_vector_type(4))) unsigned int u32x4;

static __device__ __forceinline__ short f2bf(float f) {
    __hip_bfloat16 hb = __float2bfloat16(f);
    return *reinterpret_cast<short*>(&hb);
}
static __device__ __forceinline__ float bflo(unsigned int w) {
    return __builtin_bit_cast(float, w << 16);
}
static __device__ __forceinline__ float bfhi(unsigned int w) {
    return __builtin_bit_cast(float, w & 0xffff0000u);
}

// ---- prep: blocks [0,wofs) h->bf16 ; [wofs, wofs+WCVT) W1 -> W1^T bf16 ----
__global__ __launch_bounds__(256) void prep_kernel(
    const float* __restrict__ h, const float* __restrict__ W1,
    unsigned short* __restrict__ hbf, unsigned short* __restrict__ w1t, int wofs)
{
    const int b = blockIdx.x;
    if (b < wofs) {
        int i = (b * 256 + threadIdx.x) * 4;
        f32x4 v = *reinterpret_cast<const f32x4*>(h + i);
        ushort4 o;
        o.x = (unsigned short)f2bf(v[0]);
        o.y = (unsigned short)f2bf(v[1]);
        o.z = (unsigned short)f2bf(v[2]);
        o.w = (unsigned short)f2bf(v[3]);
        *reinterpret_cast<ushort4*>(hbf + i) = o;
    } else {
        int j = ((b - wofs) * 256 + threadIdx.x) * 4;
        f32x4 w = *reinterpret_cast<const f32x4*>(W1 + j);
        int k = j >> 6, c = j & 63;
#pragma unroll
        for (int q = 0; q < 4; ++q)
            w1t[(c + q) * DIN + k] = (unsigned short)f2bf(w[q]);
    }
}

// ---- main: per wave 32 edges; 16 gathers pinned in flight; LDS B-frags ----
__global__ __launch_bounds__(256, 4) void mlp_main(
    const unsigned short* __restrict__ hbf,
    const unsigned short* __restrict__ w1t,
    const int* __restrict__ src, const int* __restrict__ dst,
    const float* __restrict__ b1, const float* __restrict__ W2,
    const float* __restrict__ b2, float* __restrict__ out)
{
    __shared__ unsigned short Blds[DH * STRK];

    const int tid = threadIdx.x;
    const int l = tid & 63;
    const int lr = l & 15;        // edge row within m-tile / hid col
    const int g = l >> 4;         // k-group (8 shorts)
    const unsigned kg = (unsigned)(g * 8);
    const int bpos = blockIdx.x * 128 + (tid >> 6) * 32;

    int p0 = bpos + lr;      if (p0 >= NEDGE) p0 = NEDGE - 1;
    int p1 = bpos + 16 + lr; if (p1 >= NEDGE) p1 = NEDGE - 1;
    const unsigned sa0 = (unsigned)src[p0] * (unsigned)DIN;
    const unsigned da0 = (unsigned)dst[p0] * (unsigned)DIN;
    const unsigned sa1 = (unsigned)src[p1] * (unsigned)DIN;
    const unsigned da1 = (unsigned)dst[p1] * (unsigned)DIN;

    // ---- issue ALL 16 gather loads; pin with a scheduling-region boundary ----
    u32x4 S0[4], D0[4], S1[4], D1[4];
#pragma unroll
    for (int ks = 0; ks < 4; ++ks) {
        S0[ks] = *reinterpret_cast<const u32x4*>(hbf + sa0 + ks * 32 + kg);
        D0[ks] = *reinterpret_cast<const u32x4*>(hbf + da0 + ks * 32 + kg);
        S1[ks] = *reinterpret_cast<const u32x4*>(hbf + sa1 + ks * 32 + kg);
        D1[ks] = *reinterpret_cast<const u32x4*>(hbf + da1 + ks * 32 + kg);
    }
    __builtin_amdgcn_sched_barrier(0);   // loads may not sink below this point

    // ---- stage W1^T into LDS while gathers fly ----
#pragma unroll
    for (int j = 0; j < 4; ++j) {
        int i = (tid + j * 256) * 8;
        int r = i >> 7, c = i & 127;
        const ushort4* ps = reinterpret_cast<const ushort4*>(w1t + i);
        ushort4 v0 = ps[0], v1 = ps[1];
        *reinterpret_cast<ushort4*>(&Blds[r * STRK + c]) = v0;
        *reinterpret_cast<ushort4*>(&Blds[r * STRK + c + 4]) = v1;
    }
    __syncthreads();

    float bv[4]; float2 w2v[4];
#pragma unroll
    for (int n = 0; n < 4; ++n) {
        bv[n] = b1[n * 16 + lr];
        w2v[n] = *reinterpret_cast<const float2*>(W2 + (n * 16 + lr) * 2);
    }
    const float bb0 = b2[0], bb1 = b2[1];

    f32x4 acc[4];

    // ================= m-tile 0 =================
#pragma unroll
    for (int n = 0; n < 4; ++n) acc[n] = (f32x4){bv[n], bv[n], bv[n], bv[n]};
#pragma unroll
    for (int ks = 0; ks < 4; ++ks) {
        bf16x8 A;
#pragma unroll
        for (int w = 0; w < 4; ++w) {
            A[2 * w]     = f2bf(bflo(S0[ks][w]) * bflo(D0[ks][w]));
            A[2 * w + 1] = f2bf(bfhi(S0[ks][w]) * bfhi(D0[ks][w]));
        }
#pragma unroll
        for (int n = 0; n < 4; ++n) {
            bf16x8 Bf = *reinterpret_cast<const bf16x8*>(
                &Blds[(n * 16 + lr) * STRK + ks * 32 + kg]);
            acc[n] = __builtin_amdgcn_mfma_f32_16x16x32_bf16(A, Bf, acc[n], 0, 0, 0);
        }
    }
    {
        float o0 = 0.f, o1 = 0.f;
#pragma unroll
        for (int r = 0; r < 4; ++r) {
            float q0 = 0.f, q1 = 0.f;
#pragma unroll
            for (int n = 0; n < 4; ++n) {
                float v = fmaxf(acc[n][r], 0.f);
                q0 = fmaf(v, w2v[n].x, q0);
                q1 = fmaf(v, w2v[n].y, q1);
            }
#pragma unroll
            for (int sh = 1; sh < 16; sh <<= 1) {
                q0 += __shfl_xor(q0, sh, 64);
                q1 += __shfl_xor(q1, sh, 64);
            }
            if (lr == r) { o0 = q0; o1 = q1; }
        }
        int epos = bpos + g * 4 + lr;           // C row = g*4 + reg
        if (lr < 4 && epos < NEDGE) {
            float2 ov = make_float2(o0 + bb0, o1 + bb1);
            *reinterpret_cast<float2*>(out + (size_t)epos * 2) = ov;
        }
    }

    // ================= m-tile 1 =================
#pragma unroll
    for (int n = 0; n < 4; ++n) acc[n] = (f32x4){bv[n], bv[n], bv[n], bv[n]};
#pragma unroll
    for (int ks = 0; ks < 4; ++ks) {
        bf16x8 A;
#pragma unroll
        for (int w = 0; w < 4; ++w) {
            A[2 * w]     = f2bf(bflo(S1[ks][w]) * bflo(D1[ks][w]));
            A[2 * w + 1] = f2bf(bfhi(S1[ks][w]) * bfhi(D1[ks][w]));
        }
#pragma unroll
        for (int n = 0; n < 4; ++n) {
            bf16x8 Bf = *reinterpret_cast<const bf16x8*>(
                &Blds[(n * 16 + lr) * STRK + ks * 32 + kg]);
            acc[n] = __builtin_amdgcn_mfma_f32_16x16x32_bf16(A, Bf, acc[n], 0, 0, 0);
        }
    }
    {
        float o0 = 0.f, o1 = 0.f;
#pragma unroll
        for (int r = 0; r < 4; ++r) {
            float q0 = 0.f, q1 = 0.f;
#pragma unroll
            for (int n = 0; n < 4; ++n) {
                float v = fmaxf(acc[n][r], 0.f);
                q0 = fmaf(v, w2v[n].x, q0);
                q1 = fmaf(v, w2v[n].y, q1);
            }
#pragma unroll
            for (int sh = 1; sh < 16; sh <<= 1) {
                q0 += __shfl_xor(q0, sh, 64);
                q1 += __shfl_xor(q1, sh, 64);
            }
            if (lr == r) { o0 = q0; o1 = q1; }
        }
        int epos = bpos + 16 + g * 4 + lr;
        if (lr < 4 && epos < NEDGE) {
            float2 ov = make_float2(o0 + bb0, o1 + bb1);
            *reinterpret_cast<float2*>(out + (size_t)epos * 2) = ov;
        }
    }
}

// ---- minimal-ws fallback: fp32 gather, global W1t ----
__global__ __launch_bounds__(256) void mlp_f32_fallback(
    const float* __restrict__ hf, const unsigned short* __restrict__ w1t,
    const float* __restrict__ b1, const float* __restrict__ W2,
    const float* __restrict__ b2, const int* __restrict__ src,
    const int* __restrict__ dst, float* __restrict__ out)
{
    const int tid = threadIdx.x;
    const int l = tid & 63, lr = l & 15, g = l >> 4;
    const unsigned kg = (unsigned)(g * 8);
    const int wbase = blockIdx.x * 64 + (tid >> 6) * 16;
    const unsigned e = (unsigned)(wbase + lr);
    const unsigned sa = (unsigned)src[e] * (unsigned)DIN;
    const unsigned da = (unsigned)dst[e] * (unsigned)DIN;
    f32x4 acc[4];
#pragma unroll
    for (int n = 0; n < 4; ++n) {
        float bvv = b1[n * 16 + lr];
        acc[n] = (f32x4){bvv, bvv, bvv, bvv};
    }
#pragma unroll
    for (int ks = 0; ks < 4; ++ks) {
        const float* ps = hf + sa + ks * 128 + g * 32;
        const float* pd = hf + da + ks * 128 + g * 32;
        f32x4 s0 = *reinterpret_cast<const f32x4*>(ps);
        f32x4 s1 = *reinterpret_cast<const f32x4*>(ps + 4);
        f32x4 d0 = *reinterpret_cast<const f32x4*>(pd);
        f32x4 d1 = *reinterpret_cast<const f32x4*>(pd + 4);
        bf16x8 A, B[4];
#pragma unroll
        for (int n = 0; n < 4; ++n)
            B[n] = *reinterpret_cast<const bf16x8*>(w1t + (n * 16 + lr) * DIN + ks * 32 + kg);
#pragma unroll
        for (int q = 0; q < 4; ++q) {
            A[q]     = f2bf(s0[q] * d0[q]);
            A[q + 4] = f2bf(s1[q] * d1[q]);
        }
#pragma unroll
        for (int n = 0; n < 4; ++n)
            acc[n] = __builtin_amdgcn_mfma_f32_16x16x32_bf16(A, B[n], acc[n], 0, 0, 0);
    }
    float2 w2v[4];
#pragma unroll
    for (int n = 0; n < 4; ++n)
        w2v[n] = *reinterpret_cast<const float2*>(W2 + (n * 16 + lr) * 2);
    const float bb0 = b2[0], bb1 = b2[1];
    float o0 = 0.f, o1 = 0.f;
#pragma unroll
    for (int r = 0; r < 4; ++r) {
        float q0 = 0.f, q1 = 0.f;
#pragma unroll
        for (int n = 0; n < 4; ++n) {
            float v = fmaxf(acc[n][r], 0.f);
            q0 = fmaf(v, w2v[n].x, q0);
            q1 = fmaf(v, w2v[n].y, q1);
        }
#pragma unroll
        for (int sh = 1; sh < 16; sh <<= 1) {
            q0 += __shfl_xor(q0, sh, 64);
            q1 += __shfl_xor(q1, sh, 64);
        }
        if (lr == r) { o0 = q0; o1 = q1; }
    }
    if (lr < 4) {
        int edge = wbase + g * 4 + lr;
        float2 ov = make_float2(o0 + bb0, o1 + bb1);
        *reinterpret_cast<float2*>(out + (size_t)edge * 2) = ov;
    }
}

extern "C" void kernel_launch(void* const* d_in, const int* in_sizes, int n_in,
                              void* d_out, int out_size, void* d_ws, size_t ws_size,
                              hipStream_t stream) {
    const float* h  = (const float*)d_in[0];
    const float* W1 = (const float*)d_in[1];
    const float* b1 = (const float*)d_in[2];
    const float* W2 = (const float*)d_in[3];
    const float* b2 = (const float*)d_in[4];
    const int* src  = (const int*)d_in[5];
    const int* dst  = (const int*)d_in[6];
    float* out = (float*)d_out;

    const size_t OFF_W1T = (size_t)NNODES * DIN * 2;     // 12,800,000
    const size_t NEED_BF = OFF_W1T + (size_t)DH * DIN * 2;
    const size_t NEED_MIN = (size_t)DH * DIN * 2;

    char* ws = (char*)d_ws;

    if (ws_size >= NEED_BF) {
        unsigned short* hbf = (unsigned short*)ws;
        unsigned short* w1t = (unsigned short*)(ws + OFF_W1T);
        prep_kernel<<<HCVT + WCVT, 256, 0, stream>>>(h, W1, hbf, w1t, HCVT);
        mlp_main<<<MAINB, 256, 0, stream>>>(hbf, w1t, src, dst, b1, W2, b2, out);
    } else if (ws_size >= NEED_MIN) {
        unsigned short* w1t = (unsigned short*)ws;
        prep_kernel<<<WCVT, 256, 0, stream>>>(h, W1, nullptr, w1t, 0);
        mlp_f32_fallback<<<NEDGE / 64, 256, 0, stream>>>(h, w1t, b1, W2, b2, src, dst, out);
    }
}

// Round 9
// 56.222 us; speedup vs baseline: 1.0914x; 1.0914x over previous
//
#include <hip/hip_runtime.h>
#include <hip/hip_bf16.h>

// Edge MLP via MFMA, round 9.
// r8 lesson: sched_barrier(0) alone cannot force the register allocator to
// keep 16 gather results live (VGPR stayed 60 -> ~8 loads in flight).
// Fix A: inline-asm global_load_dwordx4 with "=&v" outputs -- 64 dest VGPRs
//   are architecturally forced live; manual s_waitcnt vmcnt(8)/vmcnt(0) +
//   sched_barrier(0) after each (guide rule #18) give a 2-stage pipeline:
//   m-tile-0 computes while m-tile-1's 8 loads are still in flight.
//   All compiler-tracked vmem is drained at __syncthreads BEFORE the asm
//   loads, so the compiler inserts no conflicting vmcnt afterwards.
// Fix B: swapped MFMA operands: D[hid][edge] = mfma(W1t_frag, edge_frag)
//   (same fragments, swapped args). Lane l&15 then owns edge l&15's hid
//   values -> layer 2 is 16x(relu+2FMA) + only 4 shfl_xor per m-tile
//   (was 64 -> kills the 2.4M LDS bank-conflict cycles). b1/W2 come from a
//   1KB LDS Pack table: Pack[hid] = {b1, W2[hid][0], W2[hid][1], 0}.

#define NEDGE 600000
#define NNODES 50000
#define DIN 128
#define DH 64
#define STRK 136       // LDS W1t row stride (shorts)
#define HCVT 6250      // h-convert blocks
#define WCVT 8         // W1^T blocks
#define MAINB 4688     // ceil(600000/128)

typedef __attribute__((ext_vector_type(8))) short bf16x8;
typedef __attribute__((ext_vector_type(4))) float f32x4;
typedef __attribute__((ext_vector_type(4))) unsigned int u32x4;

static __device__ __forceinline__ short f2bf(float f) {
    __hip_bfloat16 hb = __float2bfloat16(f);
    return *reinterpret_cast<short*>(&hb);
}
static __device__ __forceinline__ float bflo(unsigned int w) {
    return __builtin_bit_cast(float, w << 16);
}
static __device__ __forceinline__ float bfhi(unsigned int w) {
    return __builtin_bit_cast(float, w & 0xffff0000u);
}

// ---- prep: blocks [0,wofs) h->bf16 ; [wofs, wofs+WCVT) W1 -> W1^T bf16 ----
__global__ __launch_bounds__(256) void prep_kernel(
    const float* __restrict__ h, const float* __restrict__ W1,
    unsigned short* __restrict__ hbf, unsigned short* __restrict__ w1t, int wofs)
{
    const int b = blockIdx.x;
    if (b < wofs) {
        int i = (b * 256 + threadIdx.x) * 4;
        f32x4 v = *reinterpret_cast<const f32x4*>(h + i);
        ushort4 o;
        o.x = (unsigned short)f2bf(v[0]);
        o.y = (unsigned short)f2bf(v[1]);
        o.z = (unsigned short)f2bf(v[2]);
        o.w = (unsigned short)f2bf(v[3]);
        *reinterpret_cast<ushort4*>(hbf + i) = o;
    } else {
        int j = ((b - wofs) * 256 + threadIdx.x) * 4;
        f32x4 w = *reinterpret_cast<const f32x4*>(W1 + j);
        int k = j >> 6, c = j & 63;
#pragma unroll
        for (int q = 0; q < 4; ++q)
            w1t[(c + q) * DIN + k] = (unsigned short)f2bf(w[q]);
    }
}

// force a 16-deep global-load pipeline: dest regs are asm outputs -> allocator
// must keep them live; imm offset covers the 4 k-steps (64B apart).
#define GLOAD(dst, voff, imm) \
    asm volatile("global_load_dwordx4 %0, %1, %2 offset:" imm \
                 : "=&v"(dst) : "v"(voff), "s"(hbf))

// ---- main: per wave 32 edges; swapped-operand MFMA; asm gather pipeline ----
__global__ __launch_bounds__(256, 4) void mlp_main(
    const unsigned short* __restrict__ hbf,
    const unsigned short* __restrict__ w1t,
    const int* __restrict__ src, const int* __restrict__ dst,
    const float* __restrict__ b1, const float* __restrict__ W2,
    const float* __restrict__ b2, float* __restrict__ out)
{
    __shared__ unsigned short Blds[DH * STRK];   // 17408 B
    __shared__ float4 Pack[DH];                  // 1024 B: {b1, w2x, w2y, 0}

    const int tid = threadIdx.x;
    const int l = tid & 63;
    const int lr = l & 15;        // edge (A cols in swapped D) / hid col in W1t frag
    const int g = l >> 4;         // k-group (8 shorts)
    const unsigned kg = (unsigned)(g * 8);
    const int bpos = blockIdx.x * 128 + (tid >> 6) * 32;

    int p0 = bpos + lr;      if (p0 >= NEDGE) p0 = NEDGE - 1;
    int p1 = bpos + 16 + lr; if (p1 >= NEDGE) p1 = NEDGE - 1;
    // byte offsets into hbf for this lane's 16B slice (ks folds into imm)
    const unsigned sb0 = ((unsigned)src[p0] * (unsigned)DIN + kg) * 2u;
    const unsigned db0 = ((unsigned)dst[p0] * (unsigned)DIN + kg) * 2u;
    const unsigned sb1 = ((unsigned)src[p1] * (unsigned)DIN + kg) * 2u;
    const unsigned db1 = ((unsigned)dst[p1] * (unsigned)DIN + kg) * 2u;

    // ---- stage W1^T tile + Pack table (all compiler-tracked vmem) ----
#pragma unroll
    for (int j = 0; j < 4; ++j) {
        int i = (tid + j * 256) * 8;
        int r = i >> 7, c = i & 127;
        const ushort4* ps = reinterpret_cast<const ushort4*>(w1t + i);
        ushort4 v0 = ps[0], v1 = ps[1];
        *reinterpret_cast<ushort4*>(&Blds[r * STRK + c]) = v0;
        *reinterpret_cast<ushort4*>(&Blds[r * STRK + c + 4]) = v1;
    }
    if (tid < DH) {
        float2 w2 = *reinterpret_cast<const float2*>(W2 + tid * 2);
        Pack[tid] = make_float4(b1[tid], w2.x, w2.y, 0.f);
    }
    const float bb0 = b2[0], bb1 = b2[1];
    __syncthreads();   // drains vmcnt/lgkmcnt for everything above

    // ---- issue ALL 16 gathers via asm (m0's 8 first, then m1's 8) ----
    u32x4 S0[4], D0[4], S1[4], D1[4];
    GLOAD(S0[0], sb0, "0");   GLOAD(S0[1], sb0, "64");
    GLOAD(S0[2], sb0, "128"); GLOAD(S0[3], sb0, "192");
    GLOAD(D0[0], db0, "0");   GLOAD(D0[1], db0, "64");
    GLOAD(D0[2], db0, "128"); GLOAD(D0[3], db0, "192");
    GLOAD(S1[0], sb1, "0");   GLOAD(S1[1], sb1, "64");
    GLOAD(S1[2], sb1, "128"); GLOAD(S1[3], sb1, "192");
    GLOAD(D1[0], db1, "0");   GLOAD(D1[1], db1, "64");
    GLOAD(D1[2], db1, "128"); GLOAD(D1[3], db1, "192");

    f32x4 acc[4];
    float o00, o01, o10, o11;   // m0/m1 outputs

    // ================= m-tile 0 (m1's 8 loads still in flight) =============
    asm volatile("s_waitcnt vmcnt(8)" ::: "memory");
    __builtin_amdgcn_sched_barrier(0);
#pragma unroll
    for (int n = 0; n < 4; ++n) acc[n] = (f32x4){0.f, 0.f, 0.f, 0.f};
#pragma unroll
    for (int ks = 0; ks < 4; ++ks) {
        bf16x8 A;
#pragma unroll
        for (int w = 0; w < 4; ++w) {
            A[2 * w]     = f2bf(bflo(S0[ks][w]) * bflo(D0[ks][w]));
            A[2 * w + 1] = f2bf(bfhi(S0[ks][w]) * bfhi(D0[ks][w]));
        }
#pragma unroll
        for (int n = 0; n < 4; ++n) {
            bf16x8 Wf = *reinterpret_cast<const bf16x8*>(
                &Blds[(n * 16 + lr) * STRK + ks * 32 + kg]);
            // swapped: D[hid][edge] += W1t_frag * edge_frag
            acc[n] = __builtin_amdgcn_mfma_f32_16x16x32_bf16(Wf, A, acc[n], 0, 0, 0);
        }
    }
    {
        float q0 = 0.f, q1 = 0.f;
#pragma unroll
        for (int n = 0; n < 4; ++n)
#pragma unroll
            for (int r = 0; r < 4; ++r) {
                float4 pw = Pack[n * 16 + g * 4 + r];
                float v = fmaxf(acc[n][r] + pw.x, 0.f);
                q0 = fmaf(v, pw.y, q0);
                q1 = fmaf(v, pw.z, q1);
            }
        q0 += __shfl_xor(q0, 16, 64); q0 += __shfl_xor(q0, 32, 64);
        q1 += __shfl_xor(q1, 16, 64); q1 += __shfl_xor(q1, 32, 64);
        o00 = q0 + bb0; o01 = q1 + bb1;
    }

    // ================= m-tile 1 =================
    asm volatile("s_waitcnt vmcnt(0)" ::: "memory");
    __builtin_amdgcn_sched_barrier(0);
#pragma unroll
    for (int n = 0; n < 4; ++n) acc[n] = (f32x4){0.f, 0.f, 0.f, 0.f};
#pragma unroll
    for (int ks = 0; ks < 4; ++ks) {
        bf16x8 A;
#pragma unroll
        for (int w = 0; w < 4; ++w) {
            A[2 * w]     = f2bf(bflo(S1[ks][w]) * bflo(D1[ks][w]));
            A[2 * w + 1] = f2bf(bfhi(S1[ks][w]) * bfhi(D1[ks][w]));
        }
#pragma unroll
        for (int n = 0; n < 4; ++n) {
            bf16x8 Wf = *reinterpret_cast<const bf16x8*>(
                &Blds[(n * 16 + lr) * STRK + ks * 32 + kg]);
            acc[n] = __builtin_amdgcn_mfma_f32_16x16x32_bf16(Wf, A, acc[n], 0, 0, 0);
        }
    }
    {
        float q0 = 0.f, q1 = 0.f;
#pragma unroll
        for (int n = 0; n < 4; ++n)
#pragma unroll
            for (int r = 0; r < 4; ++r) {
                float4 pw = Pack[n * 16 + g * 4 + r];
                float v = fmaxf(acc[n][r] + pw.x, 0.f);
                q0 = fmaf(v, pw.y, q0);
                q1 = fmaf(v, pw.z, q1);
            }
        q0 += __shfl_xor(q0, 16, 64); q0 += __shfl_xor(q0, 32, 64);
        q1 += __shfl_xor(q1, 16, 64); q1 += __shfl_xor(q1, 32, 64);
        o10 = q0 + bb0; o11 = q1 + bb1;
    }

    // ---- stores: lanes 0-15 own edge lr of each m-tile (contiguous 128B) ----
    if (l < 16) {
        int e0 = bpos + l;
        if (e0 < NEDGE)
            *reinterpret_cast<float2*>(out + (size_t)e0 * 2) = make_float2(o00, o01);
        int e1 = bpos + 16 + l;
        if (e1 < NEDGE)
            *reinterpret_cast<float2*>(out + (size_t)e1 * 2) = make_float2(o10, o11);
    }
}

// ---- minimal-ws fallback: fp32 gather, global W1t (r7-proven shape) ----
__global__ __launch_bounds__(256) void mlp_f32_fallback(
    const float* __restrict__ hf, const unsigned short* __restrict__ w1t,
    const float* __restrict__ b1, const float* __restrict__ W2,
    const float* __restrict__ b2, const int* __restrict__ src,
    const int* __restrict__ dst, float* __restrict__ out)
{
    const int tid = threadIdx.x;
    const int l = tid & 63, lr = l & 15, g = l >> 4;
    const unsigned kg = (unsigned)(g * 8);
    const int wbase = blockIdx.x * 64 + (tid >> 6) * 16;
    const unsigned e = (unsigned)(wbase + lr);
    const unsigned sa = (unsigned)src[e] * (unsigned)DIN;
    const unsigned da = (unsigned)dst[e] * (unsigned)DIN;
    f32x4 acc[4];
#pragma unroll
    for (int n = 0; n < 4; ++n) {
        float bvv = b1[n * 16 + lr];
        acc[n] = (f32x4){bvv, bvv, bvv, bvv};
    }
#pragma unroll
    for (int ks = 0; ks < 4; ++ks) {
        const float* ps = hf + sa + ks * 128 + g * 32;
        const float* pd = hf + da + ks * 128 + g * 32;
        f32x4 s0 = *reinterpret_cast<const f32x4*>(ps);
        f32x4 s1 = *reinterpret_cast<const f32x4*>(ps + 4);
        f32x4 d0 = *reinterpret_cast<const f32x4*>(pd);
        f32x4 d1 = *reinterpret_cast<const f32x4*>(pd + 4);
        bf16x8 A, B[4];
#pragma unroll
        for (int n = 0; n < 4; ++n)
            B[n] = *reinterpret_cast<const bf16x8*>(w1t + (n * 16 + lr) * DIN + ks * 32 + kg);
#pragma unroll
        for (int q = 0; q < 4; ++q) {
            A[q]     = f2bf(s0[q] * d0[q]);
            A[q + 4] = f2bf(s1[q] * d1[q]);
        }
#pragma unroll
        for (int n = 0; n < 4; ++n)
            acc[n] = __builtin_amdgcn_mfma_f32_16x16x32_bf16(A, B[n], acc[n], 0, 0, 0);
    }
    float2 w2v[4];
#pragma unroll
    for (int n = 0; n < 4; ++n)
        w2v[n] = *reinterpret_cast<const float2*>(W2 + (n * 16 + lr) * 2);
    const float bb0 = b2[0], bb1 = b2[1];
    float o0 = 0.f, o1 = 0.f;
#pragma unroll
    for (int r = 0; r < 4; ++r) {
        float q0 = 0.f, q1 = 0.f;
#pragma unroll
        for (int n = 0; n < 4; ++n) {
            float v = fmaxf(acc[n][r], 0.f);
            q0 = fmaf(v, w2v[n].x, q0);
            q1 = fmaf(v, w2v[n].y, q1);
        }
#pragma unroll
        for (int sh = 1; sh < 16; sh <<= 1) {
            q0 += __shfl_xor(q0, sh, 64);
            q1 += __shfl_xor(q1, sh, 64);
        }
        if (lr == r) { o0 = q0; o1 = q1; }
    }
    if (lr < 4) {
        int edge = wbase + g * 4 + lr;
        float2 ov = make_float2(o0 + bb0, o1 + bb1);
        *reinterpret_cast<float2*>(out + (size_t)edge * 2) = ov;
    }
}

extern "C" void kernel_launch(void* const* d_in, const int* in_sizes, int n_in,
                              void* d_out, int out_size, void* d_ws, size_t ws_size,
                              hipStream_t stream) {
    const float* h  = (const float*)d_in[0];
    const float* W1 = (const float*)d_in[1];
    const float* b1 = (const float*)d_in[2];
    const float* W2 = (const float*)d_in[3];
    const float* b2 = (const float*)d_in[4];
    const int* src  = (const int*)d_in[5];
    const int* dst  = (const int*)d_in[6];
    float* out = (float*)d_out;

    const size_t OFF_W1T = (size_t)NNODES * DIN * 2;     // 12,800,000
    const size_t NEED_BF = OFF_W1T + (size_t)DH * DIN * 2;
    const size_t NEED_MIN = (size_t)DH * DIN * 2;

    char* ws = (char*)d_ws;

    if (ws_size >= NEED_BF) {
        unsigned short* hbf = (unsigned short*)ws;
        unsigned short* w1t = (unsigned short*)(ws + OFF_W1T);
        prep_kernel<<<HCVT + WCVT, 256, 0, stream>>>(h, W1, hbf, w1t, HCVT);
        mlp_main<<<MAINB, 256, 0, stream>>>(hbf, w1t, src, dst, b1, W2, b2, out);
    } else if (ws_size >= NEED_MIN) {
        unsigned short* w1t = (unsigned short*)ws;
        prep_kernel<<<WCVT, 256, 0, stream>>>(h, W1, nullptr, w1t, 0);
        mlp_f32_fallback<<<NEDGE / 64, 256, 0, stream>>>(h, w1t, b1, W2, b2, src, dst, out);
    }
}